// Round 6
// baseline (238.179 us; speedup 1.0000x reference)
//
#include <hip/hip_runtime.h>
#include <hip/hip_bf16.h>
#include <math.h>
#include <stdint.h>

#define B_ 64
#define L_ 2048
#define H_ 128
#define O_ 128
#define N_ 256
#define CH_ 128      // timesteps per chunk
#define NCH_ 16      // chunks
#define SPC_ 8       // strips (16 t) per chunk

using f32x4 = __attribute__((ext_vector_type(4))) float;
using i32x4 = __attribute__((ext_vector_type(4))) int;
using h16x8 = __attribute__((ext_vector_type(8))) _Float16;

__device__ __forceinline__ unsigned short f16_bits(float v) {
    _Float16 h = (_Float16)v;                 // RNE convert
    return __builtin_bit_cast(unsigned short, h);
}
__device__ __forceinline__ int pack_f16(float a, float b) {
    return (int)((unsigned)f16_bits(a) | ((unsigned)f16_bits(b) << 16));
}

// LDS-only barrier: waits own ds ops, does NOT drain global loads (unlike
// __syncthreads, which emits s_waitcnt vmcnt(0) and kills prefetch).
#define BAR_LDS() asm volatile("s_waitcnt lgkmcnt(0)\n\ts_barrier" ::: "memory")

// ---------------------------------------------------------------------------
// prep: every block self-computes the nu-sorted permutation (rank 0 = slowest
// decay), then fills its slice of: B2Tr (fp16 (gamma*B)^T, rank-ordered cols),
// lamjR[rank][j]=lam^(15-j), lam16R=lam^16, lamCCr[c][rank]=lam^(128*(15-c)),
// nuR, perm, and zeroes X.
// ---------------------------------------------------------------------------
__global__ void prep_kernel(const float* __restrict__ nu_log, const float* __restrict__ theta_log,
                            const float* __restrict__ gamma_log, const float* __restrict__ B_re,
                            const float* __restrict__ B_im, unsigned short* __restrict__ B2Tr,
                            float2* __restrict__ lamjR, float2* __restrict__ lam16R,
                            float2* __restrict__ lamCCr, float* __restrict__ nuR,
                            int* __restrict__ perm, float* __restrict__ X) {
    __shared__ float nu_s[N_];
    __shared__ int perm_s[N_];
    const int t = threadIdx.x;
    float nu = expf(nu_log[t]);
    nu_s[t] = nu;
    __syncthreads();
    {
        int rank = 0;
        for (int j = 0; j < N_; ++j) {
            float vj = nu_s[j];
            rank += (vj < nu || (vj == nu && j < t)) ? 1 : 0;
        }
        perm_s[rank] = t;
    }
    __syncthreads();
    const int bb = blockIdx.x;
    if (bb < 64) {
        #pragma unroll
        for (int kk = 0; kk < 4; ++kk) {
            int e = bb * 1024 + kk * 256 + t;       // 0..65535
            int part = e >> 15, rank = (e >> 7) & 255, h = e & 127;
            int n = perm_s[rank];
            float g = expf(gamma_log[n]);
            float v = (part ? B_im : B_re)[n * H_ + h] * g;
            B2Tr[e] = f16_bits(v);
        }
    } else if (bb == 64) {
        int r = t, n = perm_s[r];
        float nun = nu_s[n];
        double th = (double)expf(theta_log[n]);
        double rr = exp(-(double)nun);
        double sn, cs;
        sincos(th, &sn, &cs);
        double lre = rr * cs, lim = rr * sn;
        double pre = 1.0, pim = 0.0;
        for (int k = 0; k < 16; ++k) {
            lamjR[r * 16 + 15 - k] = make_float2((float)pre, (float)pim);
            double t1 = pre * lre - pim * lim, t2 = pre * lim + pim * lre;
            pre = t1; pim = t2;
        }
        lam16R[r] = make_float2((float)pre, (float)pim);   // lam^16
        nuR[r] = nun;
        perm[r] = n;
        double wre = pre, wim = pim;                        // -> lam^128
        for (int i = 0; i < 3; ++i) {
            double a = wre * wre - wim * wim, b2 = 2.0 * wre * wim;
            wre = a; wim = b2;
        }
        double are = 1.0, aim = 0.0;
        for (int c = 15; c >= 0; --c) {
            lamCCr[c * N_ + r] = make_float2((float)are, (float)aim);
            double a = are * wre - aim * wim, b2 = are * wim + aim * wre;
            are = a; aim = b2;
        }
    } else {
        int idx = (bb - 65) * 1024 + t * 4;                 // 32 blocks x 1024 floats
        f32x4 z = {0.f, 0.f, 0.f, 0.f};
        *(f32x4*)&X[idx] = z;
    }
}

// ---------------------------------------------------------------------------
// scan: 256-thr block = (half, chunk c, b), heavy half first in dispatch
// order. 4 waves; wave w owns group g = half*4 + w (32 ranks = 2 pairs).
// u strips (16t x 128h) staged into fp16 LDS (double-buffered, XOR-swizzled),
// 3-deep prefetch in NAMED registers (a0..a2/b0..b2 — no spillable arrays),
// and an LDS-only barrier per strip so global prefetches stay in flight.
// z <- lam^16 z + sum_j lam^(15-j) Bu_j; dead pairs/strips skipped via the
// nu-sorted decay windows; epilogue rotates by lamCC, atomicAdds complex x.
// ---------------------------------------------------------------------------
__global__ __launch_bounds__(256, 4)
void scan_kernel(const float* __restrict__ u, const unsigned short* __restrict__ B2Tr,
                 const float2* __restrict__ lamjR, const float2* __restrict__ lam16R,
                 const float2* __restrict__ lamCCr, const float* __restrict__ nuR,
                 const int* __restrict__ perm, float* __restrict__ X) {
    const int bx = blockIdx.x;
    const int half = bx >> 10;
    const int c = (bx >> 6) & 15;
    const int b = bx & 63;
    const int tid = threadIdx.x;
    const int wave = tid >> 6, lane = tid & 63;
    const int m = lane & 15, q = lane >> 4;
    const int g = half * 4 + wave;

    // strip alive iff nu*(base_e - 16s) <= 35  (e^-35 ~ 6e-16 truncation)
    const float base_e = 2032.0f - 128.0f * (float)c;
    int sblk = (int)ceilf((base_e - 35.0f / nuR[half * 128]) * 0.0625f);
    if (sblk >= SPC_) return;                 // whole block dead (uniform)
    if (sblk < 0) sblk = 0;
    int sp0 = (int)ceilf((base_e - 35.0f / nuR[g * 32]) * 0.0625f);
    if (sp0 < 0) sp0 = 0;
    int sp1 = (int)ceilf((base_e - 35.0f / nuR[g * 32 + 16]) * 0.0625f);
    if (sp1 < 0) sp1 = 0;                     // sp0/sp1 may be >= SPC_ (dead pair)
    const int live = SPC_ - sblk;             // 1..8 strips to process

    __shared__ __align__(16) unsigned short ubuf[2][16 * 128];   // fp16, 2 x 4 KB

    // B fragments (fp16) + fold weights (fp32), reused over all strips
    h16x8 bf[2][2][4];
    float2 wl[2][4];
    float2 l16[2];
    #pragma unroll
    for (int p = 0; p < 2; ++p) {
        const int rank = g * 32 + p * 16 + m;
        #pragma unroll
        for (int part = 0; part < 2; ++part) {
            const unsigned short* rp = B2Tr + (size_t)(part * N_ + rank) * H_ + q * 8;
            #pragma unroll
            for (int sl = 0; sl < 4; ++sl)
                bf[p][part][sl] = *(const h16x8*)(rp + sl * 32);
        }
        #pragma unroll
        for (int r = 0; r < 4; ++r) wl[p][r] = lamjR[rank * 16 + q * 4 + r];
        l16[p] = lam16R[rank];
    }

    float2 zr[2], zi[2];
    #pragma unroll
    for (int p = 0; p < 2; ++p) { zr[p] = make_float2(0.f, 0.f); zi[p] = make_float2(0.f, 0.f); }

    // staging coords: thread t -> row sr (0..15), 8-float unit sg (0..15)
    const int sr = tid >> 4, sg = tid & 15;
    const float* gbase = u + ((size_t)b * L_ + (size_t)(c * CH_ + sblk * 16)) * H_
                           + (size_t)sr * H_ + sg * 8;
    unsigned short* lwr = &ubuf[0][0] + sr * 128 + ((sg ^ sr) * 8);   // swizzled unit
    const int bufStride = 16 * 128;

    // named prefetch slots (strip k -> slot k%3); literal indices only
    float4 a0, b0, a1, b1, a2, b2;

#define LOADS(slot, idx) { const float* p4_ = gbase + (size_t)(idx) * (16 * H_); \
        a##slot = *(const float4*)p4_; b##slot = *(const float4*)(p4_ + 4); }
#define STORES(slot, bufi) { i32x4 w_; \
        w_[0] = pack_f16(a##slot.x, a##slot.y);  w_[1] = pack_f16(a##slot.z, a##slot.w); \
        w_[2] = pack_f16(b##slot.x, b##slot.y);  w_[3] = pack_f16(b##slot.z, b##slot.w); \
        *(i32x4*)(lwr + (bufi) * bufStride) = w_; }

    auto compute = [&](const unsigned short* lb, int s) {
        h16x8 afr[4];
        #pragma unroll
        for (int sl = 0; sl < 4; ++sl) {
            const int unit = (sl * 4 + q) ^ m;   // matches writer swizzle
            afr[sl] = *(const h16x8*)(lb + m * 128 + unit * 8);
        }
        #pragma unroll
        for (int p = 0; p < 2; ++p) {
            const int sp = p ? sp1 : sp0;
            if (s < sp) continue;                 // wave-uniform
            float2 t0 = zr[p];
            zr[p].x = l16[p].x * t0.x - l16[p].y * t0.y;
            zr[p].y = l16[p].x * t0.y + l16[p].y * t0.x;
            float2 t1 = zi[p];
            zi[p].x = l16[p].x * t1.x - l16[p].y * t1.y;
            zi[p].y = l16[p].x * t1.y + l16[p].y * t1.x;
            f32x4 acc = {0.f, 0.f, 0.f, 0.f};
            #pragma unroll
            for (int sl = 0; sl < 4; ++sl)
                acc = __builtin_amdgcn_mfma_f32_16x16x32_f16(afr[sl], bf[p][0][sl], acc, 0, 0, 0);
            #pragma unroll
            for (int r = 0; r < 4; ++r) {
                zr[p].x += wl[p][r].x * acc[r];
                zr[p].y += wl[p][r].y * acc[r];
            }
            f32x4 acc2 = {0.f, 0.f, 0.f, 0.f};
            #pragma unroll
            for (int sl = 0; sl < 4; ++sl)
                acc2 = __builtin_amdgcn_mfma_f32_16x16x32_f16(afr[sl], bf[p][1][sl], acc2, 0, 0, 0);
            #pragma unroll
            for (int r = 0; r < 4; ++r) {
                zi[p].x += wl[p][r].x * acc2[r];
                zi[p].y += wl[p][r].y * acc2[r];
            }
        }
    };

    // prologue: issue strips 0..2, stage strip 0 -> buf 0
    LOADS(0, 0);
    if (1 < live) LOADS(1, 1);
    if (2 < live) LOADS(2, 2);
    STORES(0, 0);
    BAR_LDS();

    // iteration i: read buf i&1; stage strip i+1 (slot (i+1)%3) -> buf (i+1)&1;
    // issue loads for strip i+3 (slot (i+3)%3); LDS-only barrier.
#define ITER(i, lslot, wslot) \
    if ((i) < live) { \
        if ((i) + 3 < live) LOADS(lslot, (i) + 3); \
        if ((i) + 1 < live) STORES(wslot, ((i) + 1) & 1); \
        compute(&ubuf[(i) & 1][0], sblk + (i)); \
        BAR_LDS(); \
    }

    ITER(0, 0, 1)
    ITER(1, 1, 2)
    ITER(2, 2, 0)
    ITER(3, 0, 1)
    ITER(4, 1, 2)
    ITER(5, 2, 0)
    ITER(6, 0, 1)
    ITER(7, 1, 2)
#undef ITER
#undef LOADS
#undef STORES

    // epilogue: reduce over q, rotate by lamCC, atomic complex partials
    #pragma unroll
    for (int p = 0; p < 2; ++p) {
        const int sp = p ? sp1 : sp0;
        if (sp >= SPC_) continue;                 // pair never ran
        float a = zr[p].x, b2 = zr[p].y, c2 = zi[p].x, d2 = zi[p].y;
        a  += __shfl_xor(a, 16);  a  += __shfl_xor(a, 32);
        b2 += __shfl_xor(b2, 16); b2 += __shfl_xor(b2, 32);
        c2 += __shfl_xor(c2, 16); c2 += __shfl_xor(c2, 32);
        d2 += __shfl_xor(d2, 16); d2 += __shfl_xor(d2, 32);
        if (lane < 16) {
            const int rank = g * 32 + p * 16 + m;
            const int n = perm[rank];
            float2 lc = lamCCr[c * N_ + rank];
            float prr = lc.x * a - lc.y * b2;
            float pri = lc.x * b2 + lc.y * a;
            float pir = lc.x * c2 - lc.y * d2;
            float pii = lc.x * d2 + lc.y * c2;
            atomicAdd(&X[(size_t)(b * N_ + n) * 2 + 0], prr - pii);
            atomicAdd(&X[(size_t)(b * N_ + n) * 2 + 1], pri + pir);
        }
    }
}

// ---------------------------------------------------------------------------
// out: y[b,o] = sum_n (Cre*Xre - Cim*Xim) + sum_h D[o,h]*u[b,L-1,h]
// ---------------------------------------------------------------------------
__global__ void out_kernel(const float* __restrict__ X, const float* __restrict__ C_re,
                           const float* __restrict__ C_im, const float* __restrict__ Dm,
                           const float* __restrict__ u, float* __restrict__ out) {
    __shared__ float xre[N_], xim[N_], ul[H_];
    const int b = blockIdx.x;
    const int t = threadIdx.x;
    xre[t] = X[(size_t)(b * N_ + t) * 2 + 0];
    xim[t] = X[(size_t)(b * N_ + t) * 2 + 1];
    if (t < H_) ul[t] = u[((size_t)b * L_ + (L_ - 1)) * H_ + t];
    __syncthreads();
    const int o = t >> 1;
    const int h = t & 1;
    const float* cre = C_re + o * N_ + h * 128;
    const float* cim = C_im + o * N_ + h * 128;
    const float* xr = xre + h * 128;
    const float* xi = xim + h * 128;
    float s = 0.f;
    #pragma unroll 4
    for (int n = 0; n < 128; ++n) s += cre[n] * xr[n] - cim[n] * xi[n];
    const float* dp = Dm + o * H_ + h * 64;
    const float* up = ul + h * 64;
    #pragma unroll 4
    for (int k = 0; k < 64; ++k) s += dp[k] * up[k];
    s += __shfl_xor(s, 1);
    if (h == 0) out[b * O_ + o] = s;
}

extern "C" void kernel_launch(void* const* d_in, const int* in_sizes, int n_in,
                              void* d_out, int out_size, void* d_ws, size_t ws_size,
                              hipStream_t stream) {
    const float* u         = (const float*)d_in[2];   // dynamics_disturbance_time_window
    const float* nu_log    = (const float*)d_in[3];
    const float* theta_log = (const float*)d_in[4];
    const float* gamma_log = (const float*)d_in[5];
    const float* B_re      = (const float*)d_in[6];
    const float* B_im      = (const float*)d_in[7];
    const float* C_re      = (const float*)d_in[8];
    const float* C_im      = (const float*)d_in[9];
    const float* Dm        = (const float*)d_in[10];

    char* ws = (char*)d_ws;
    float*          X      = (float*)ws;                       // 131072 B
    unsigned short* B2Tr   = (unsigned short*)(ws + 131072);   // 131072 B
    float2*         lamjR  = (float2*)(ws + 262144);           // 32768 B
    float2*         lam16R = (float2*)(ws + 294912);           // 2048 B
    float2*         lamCCr = (float2*)(ws + 296960);           // 32768 B
    float*          nuR    = (float*)(ws + 329728);            // 1024 B
    int*            perm   = (int*)(ws + 330752);              // 1024 B

    prep_kernel<<<97, 256, 0, stream>>>(nu_log, theta_log, gamma_log, B_re, B_im,
                                        B2Tr, lamjR, lam16R, lamCCr, nuR, perm, X);
    scan_kernel<<<B_ * NCH_ * 2, 256, 0, stream>>>(u, B2Tr, lamjR, lam16R, lamCCr, nuR, perm, X);
    out_kernel<<<B_, 256, 0, stream>>>(X, C_re, C_im, Dm, u, (float*)d_out);
}

// Round 7
// 186.491 us; speedup vs baseline: 1.2772x; 1.2772x over previous
//
#include <hip/hip_runtime.h>
#include <hip/hip_bf16.h>
#include <math.h>
#include <stdint.h>

#define B_ 64
#define L_ 2048
#define H_ 128
#define O_ 128
#define N_ 256
#define CH_ 128      // timesteps per chunk
#define NCH_ 16      // chunks
#define SPC_ 8       // strips (16 t) per chunk

using f32x4 = __attribute__((ext_vector_type(4))) float;
using i32x4 = __attribute__((ext_vector_type(4))) int;
using h16x8 = __attribute__((ext_vector_type(8))) _Float16;

__device__ __forceinline__ unsigned short f16_bits(float v) {
    _Float16 h = (_Float16)v;                 // RNE convert
    return __builtin_bit_cast(unsigned short, h);
}
__device__ __forceinline__ int pack_f16(float a, float b) {
    return (int)((unsigned)f16_bits(a) | ((unsigned)f16_bits(b) << 16));
}

// ---------------------------------------------------------------------------
// prep: every block self-computes the nu-sorted permutation (rank 0 = slowest
// decay), then fills its slice of: B2Tr (fp16 (gamma*B)^T, rank-ordered cols),
// lamjR[rank][j]=lam^(15-j), lam16R=lam^16, lamCCr[c][rank]=lam^(128*(15-c)),
// nuR, perm, and zeroes X.
// ---------------------------------------------------------------------------
__global__ void prep_kernel(const float* __restrict__ nu_log, const float* __restrict__ theta_log,
                            const float* __restrict__ gamma_log, const float* __restrict__ B_re,
                            const float* __restrict__ B_im, unsigned short* __restrict__ B2Tr,
                            float2* __restrict__ lamjR, float2* __restrict__ lam16R,
                            float2* __restrict__ lamCCr, float* __restrict__ nuR,
                            int* __restrict__ perm, float* __restrict__ X) {
    __shared__ float nu_s[N_];
    __shared__ int perm_s[N_];
    const int t = threadIdx.x;
    float nu = expf(nu_log[t]);
    nu_s[t] = nu;
    __syncthreads();
    {
        int rank = 0;
        for (int j = 0; j < N_; ++j) {
            float vj = nu_s[j];
            rank += (vj < nu || (vj == nu && j < t)) ? 1 : 0;
        }
        perm_s[rank] = t;
    }
    __syncthreads();
    const int bb = blockIdx.x;
    if (bb < 64) {
        #pragma unroll
        for (int kk = 0; kk < 4; ++kk) {
            int e = bb * 1024 + kk * 256 + t;       // 0..65535
            int part = e >> 15, rank = (e >> 7) & 255, h = e & 127;
            int n = perm_s[rank];
            float g = expf(gamma_log[n]);
            float v = (part ? B_im : B_re)[n * H_ + h] * g;
            B2Tr[e] = f16_bits(v);
        }
    } else if (bb == 64) {
        int r = t, n = perm_s[r];
        float nun = nu_s[n];
        double th = (double)expf(theta_log[n]);
        double rr = exp(-(double)nun);
        double sn, cs;
        sincos(th, &sn, &cs);
        double lre = rr * cs, lim = rr * sn;
        double pre = 1.0, pim = 0.0;
        for (int k = 0; k < 16; ++k) {
            lamjR[r * 16 + 15 - k] = make_float2((float)pre, (float)pim);
            double t1 = pre * lre - pim * lim, t2 = pre * lim + pim * lre;
            pre = t1; pim = t2;
        }
        lam16R[r] = make_float2((float)pre, (float)pim);   // lam^16
        nuR[r] = nun;
        perm[r] = n;
        double wre = pre, wim = pim;                        // -> lam^128
        for (int i = 0; i < 3; ++i) {
            double a = wre * wre - wim * wim, b2 = 2.0 * wre * wim;
            wre = a; wim = b2;
        }
        double are = 1.0, aim = 0.0;
        for (int c = 15; c >= 0; --c) {
            lamCCr[c * N_ + r] = make_float2((float)are, (float)aim);
            double a = are * wre - aim * wim, b2 = are * wim + aim * wre;
            are = a; aim = b2;
        }
    } else {
        int idx = (bb - 65) * 1024 + t * 4;                 // 32 blocks x 1024 floats
        f32x4 z = {0.f, 0.f, 0.f, 0.f};
        *(f32x4*)&X[idx] = z;
    }
}

// ---------------------------------------------------------------------------
// scan: block = (b, chunk c), 512 threads = 8 waves.
// Phase 1 (bulk, max MLP): each thread loads 128 contiguous bytes of u
// (8 independent dwordx4), packs to fp16, stores to a 32 KB XOR-swizzled LDS
// image of the whole chunk (128 t x 128 h). ONE __syncthreads.
// Phase 2 (LDS-only): wave g owns ranks g*32..g*32+31 (2 pairs). Pair-outer:
// z <- lam^16 z + sum_j lam^(15-j) Bu_j per strip, strips below the decay
// window skipped. Epilogue rotates by lamCC and atomicAdds complex x[b,n].
// Bank math: row stride 256 B, unit swizzle ^ (row & 15) -> both the b128
// writes (phase 1) and b128 reads (phase 2) spread uniformly over 32 banks.
// ---------------------------------------------------------------------------
__global__ __launch_bounds__(512, 4)
void scan_kernel(const float* __restrict__ u, const unsigned short* __restrict__ B2Tr,
                 const float2* __restrict__ lamjR, const float2* __restrict__ lam16R,
                 const float2* __restrict__ lamCCr, const float* __restrict__ nuR,
                 const int* __restrict__ perm, float* __restrict__ X) {
    const int bx = blockIdx.x;
    const int c = bx & 15;
    const int b = bx >> 4;
    const int tid = threadIdx.x;

    __shared__ __align__(16) unsigned short Asm[CH_ * H_];   // 32 KB fp16 chunk image

    // ---- phase 1: stage the whole chunk ----
    {
        const int r = tid >> 2;            // chunk-local timestep 0..127
        const int qq = tid & 3;            // 32-float column quarter
        const float* gsrc = u + ((size_t)b * L_ + (size_t)(c * CH_ + r)) * H_ + qq * 32;
        f32x4 Lv[8];
        #pragma unroll
        for (int k = 0; k < 8; ++k) Lv[k] = *(const f32x4*)(gsrc + k * 4);
        #pragma unroll
        for (int j = 0; j < 4; ++j) {
            const int unit = (qq * 4 + j) ^ (r & 15);
            i32x4 w;
            w[0] = pack_f16(Lv[2 * j][0], Lv[2 * j][1]);
            w[1] = pack_f16(Lv[2 * j][2], Lv[2 * j][3]);
            w[2] = pack_f16(Lv[2 * j + 1][0], Lv[2 * j + 1][1]);
            w[3] = pack_f16(Lv[2 * j + 1][2], Lv[2 * j + 1][3]);
            *(i32x4*)&Asm[r * H_ + unit * 8] = w;
        }
    }
    __syncthreads();

    // ---- phase 2: per-wave MFMA from LDS ----
    const int g = tid >> 6;                // rank group 0..7
    const int lane = tid & 63;
    const int m = lane & 15, q = lane >> 4;

    // strip alive iff nu*(base_e - 16s) <= 35  (e^-35 ~ 6e-16 truncation)
    const float base_e = 2032.0f - 128.0f * (float)c;
    int sp0 = (int)ceilf((base_e - 35.0f / nuR[g * 32]) * 0.0625f);
    if (sp0 < 0) sp0 = 0;
    int sp1 = (int)ceilf((base_e - 35.0f / nuR[g * 32 + 16]) * 0.0625f);
    if (sp1 < 0) sp1 = 0;

    if (sp0 < SPC_) {                      // wave has live work (sp0 <= sp1)
        #pragma unroll
        for (int p = 0; p < 2; ++p) {
            const int sp = p ? sp1 : sp0;
            if (sp >= SPC_) continue;      // pair dead (wave-uniform)
            const int rank = g * 32 + p * 16 + m;

            h16x8 bfr[2][4];
            #pragma unroll
            for (int part = 0; part < 2; ++part) {
                const unsigned short* rp = B2Tr + (size_t)(part * N_ + rank) * H_ + q * 8;
                #pragma unroll
                for (int sl = 0; sl < 4; ++sl)
                    bfr[part][sl] = *(const h16x8*)(rp + sl * 32);
            }
            float2 wl[4];
            #pragma unroll
            for (int r2 = 0; r2 < 4; ++r2) wl[r2] = lamjR[rank * 16 + q * 4 + r2];
            const float2 l16 = lam16R[rank];

            float2 zre = make_float2(0.f, 0.f), zim = make_float2(0.f, 0.f);
            for (int s = sp; s < SPC_; ++s) {
                const int row = s * 16 + m;
                h16x8 afr[4];
                #pragma unroll
                for (int sl = 0; sl < 4; ++sl) {
                    const int unit = (sl * 4 + q) ^ m;
                    afr[sl] = *(const h16x8*)&Asm[row * H_ + unit * 8];
                }
                // rescale accumulators by lam^16
                float2 t0 = zre;
                zre.x = l16.x * t0.x - l16.y * t0.y;
                zre.y = l16.x * t0.y + l16.y * t0.x;
                float2 t1 = zim;
                zim.x = l16.x * t1.x - l16.y * t1.y;
                zim.y = l16.x * t1.y + l16.y * t1.x;
                f32x4 acc = {0.f, 0.f, 0.f, 0.f};
                #pragma unroll
                for (int sl = 0; sl < 4; ++sl)
                    acc = __builtin_amdgcn_mfma_f32_16x16x32_f16(afr[sl], bfr[0][sl], acc, 0, 0, 0);
                #pragma unroll
                for (int r2 = 0; r2 < 4; ++r2) {
                    zre.x += wl[r2].x * acc[r2];
                    zre.y += wl[r2].y * acc[r2];
                }
                f32x4 acc2 = {0.f, 0.f, 0.f, 0.f};
                #pragma unroll
                for (int sl = 0; sl < 4; ++sl)
                    acc2 = __builtin_amdgcn_mfma_f32_16x16x32_f16(afr[sl], bfr[1][sl], acc2, 0, 0, 0);
                #pragma unroll
                for (int r2 = 0; r2 < 4; ++r2) {
                    zim.x += wl[r2].x * acc2[r2];
                    zim.y += wl[r2].y * acc2[r2];
                }
            }

            // reduce over q, rotate by lamCC, atomic complex partials
            float a = zre.x, b2 = zre.y, c2 = zim.x, d2 = zim.y;
            a  += __shfl_xor(a, 16);  a  += __shfl_xor(a, 32);
            b2 += __shfl_xor(b2, 16); b2 += __shfl_xor(b2, 32);
            c2 += __shfl_xor(c2, 16); c2 += __shfl_xor(c2, 32);
            d2 += __shfl_xor(d2, 16); d2 += __shfl_xor(d2, 32);
            if (lane < 16) {
                const int n = perm[rank];
                float2 lc = lamCCr[c * N_ + rank];
                float prr = lc.x * a - lc.y * b2;
                float pri = lc.x * b2 + lc.y * a;
                float pir = lc.x * c2 - lc.y * d2;
                float pii = lc.x * d2 + lc.y * c2;
                atomicAdd(&X[(size_t)(b * N_ + n) * 2 + 0], prr - pii);
                atomicAdd(&X[(size_t)(b * N_ + n) * 2 + 1], pri + pir);
            }
        }
    }
}

// ---------------------------------------------------------------------------
// out: y[b,o] = sum_n (Cre*Xre - Cim*Xim) + sum_h D[o,h]*u[b,L-1,h]
// ---------------------------------------------------------------------------
__global__ void out_kernel(const float* __restrict__ X, const float* __restrict__ C_re,
                           const float* __restrict__ C_im, const float* __restrict__ Dm,
                           const float* __restrict__ u, float* __restrict__ out) {
    __shared__ float xre[N_], xim[N_], ul[H_];
    const int b = blockIdx.x;
    const int t = threadIdx.x;
    xre[t] = X[(size_t)(b * N_ + t) * 2 + 0];
    xim[t] = X[(size_t)(b * N_ + t) * 2 + 1];
    if (t < H_) ul[t] = u[((size_t)b * L_ + (L_ - 1)) * H_ + t];
    __syncthreads();
    const int o = t >> 1;
    const int h = t & 1;
    const float* cre = C_re + o * N_ + h * 128;
    const float* cim = C_im + o * N_ + h * 128;
    const float* xr = xre + h * 128;
    const float* xi = xim + h * 128;
    float s = 0.f;
    #pragma unroll 4
    for (int n = 0; n < 128; ++n) s += cre[n] * xr[n] - cim[n] * xi[n];
    const float* dp = Dm + o * H_ + h * 64;
    const float* up = ul + h * 64;
    #pragma unroll 4
    for (int k = 0; k < 64; ++k) s += dp[k] * up[k];
    s += __shfl_xor(s, 1);
    if (h == 0) out[b * O_ + o] = s;
}

extern "C" void kernel_launch(void* const* d_in, const int* in_sizes, int n_in,
                              void* d_out, int out_size, void* d_ws, size_t ws_size,
                              hipStream_t stream) {
    const float* u         = (const float*)d_in[2];   // dynamics_disturbance_time_window
    const float* nu_log    = (const float*)d_in[3];
    const float* theta_log = (const float*)d_in[4];
    const float* gamma_log = (const float*)d_in[5];
    const float* B_re      = (const float*)d_in[6];
    const float* B_im      = (const float*)d_in[7];
    const float* C_re      = (const float*)d_in[8];
    const float* C_im      = (const float*)d_in[9];
    const float* Dm        = (const float*)d_in[10];

    char* ws = (char*)d_ws;
    float*          X      = (float*)ws;                       // 131072 B
    unsigned short* B2Tr   = (unsigned short*)(ws + 131072);   // 131072 B
    float2*         lamjR  = (float2*)(ws + 262144);           // 32768 B
    float2*         lam16R = (float2*)(ws + 294912);           // 2048 B
    float2*         lamCCr = (float2*)(ws + 296960);           // 32768 B
    float*          nuR    = (float*)(ws + 329728);            // 1024 B
    int*            perm   = (int*)(ws + 330752);              // 1024 B

    prep_kernel<<<97, 256, 0, stream>>>(nu_log, theta_log, gamma_log, B_re, B_im,
                                        B2Tr, lamjR, lam16R, lamCCr, nuR, perm, X);
    scan_kernel<<<B_ * NCH_, 512, 0, stream>>>(u, B2Tr, lamjR, lam16R, lamCCr, nuR, perm, X);
    out_kernel<<<B_, 256, 0, stream>>>(X, C_re, C_im, Dm, u, (float*)d_out);
}